// Round 11
// baseline (290.048 us; speedup 1.0000x reference)
//
#include <hip/hip_runtime.h>
#include <cstdint>
#include <cstddef>

typedef unsigned short u16;
typedef __bf16 bf16x8 __attribute__((ext_vector_type(8)));
typedef float f32x4 __attribute__((ext_vector_type(4)));

#define KOFF 27
#define EPSBN 1e-5f

__device__ inline u16 f2bf(float f) {
  unsigned int u = __float_as_uint(f);
  unsigned int r = (u + 0x7FFFu + ((u >> 16) & 1u)) >> 16;  // RNE
  return (u16)r;
}
__device__ inline float bf2f(u16 h) {
  return __uint_as_float(((unsigned int)h) << 16);
}

typedef const __attribute__((address_space(1))) void ga_void;
typedef __attribute__((address_space(3))) void lds_void;
__device__ __forceinline__ void gload_lds16(const void* g, void* l) {
  __builtin_amdgcn_global_load_lds((ga_void*)g, (lds_void*)l, 16, 0, 0);
}

// ---------------- fused prep kernel ----------------
// blocks [0, gN): transpose nbr [N,27] -> nbrT [27,N]; plane 27 = all -1
//   (padding consumed by the k=26 stage; plane 28 is allocated-but-garbage,
//    read once into registers that are never used).
// blocks [gN, gN+gW): pack W1 into MFMA B-frag order (bf16)
// blocks [gN+gW, gN+2gW): pack W2
// blocks [gN+2gW, ...): cast feats->bf16 (first block zeroes stats + zero-page)
__global__ void k_prep(const float* __restrict__ feats, const float* __restrict__ W1,
                       const float* __restrict__ W2, const int* __restrict__ nbr,
                       u16* __restrict__ featsb, u16* __restrict__ w1p,
                       u16* __restrict__ w2p, int* __restrict__ nbrT,
                       float* __restrict__ stats, float* __restrict__ zbuf,
                       int N, int gN, int gW, int n4) {
  __shared__ int L[64 * KOFF];
  const int t = threadIdx.x;
  const int bid = blockIdx.x;

  if (bid < gN) {  // neighbor transpose
    const int v0 = bid * 64;
    const int nv = min(64, N - v0);
    const int cnt = nv * KOFF;
    for (int i = t; i < cnt; i += 256) L[i] = nbr[(size_t)v0 * KOFF + i];
    __syncthreads();
    for (int i = t; i < KOFF * 64; i += 256) {
      int k = i >> 6, j = i & 63;
      if (j < nv) nbrT[(size_t)k * N + v0 + j] = L[j * KOFF + k];
    }
    if (t < nv) nbrT[(size_t)KOFF * N + v0 + t] = -1;  // plane 27 padding
    return;
  }
  if (bid < gN + 2 * gW) {  // weight pack
    const int wi = bid - gN;
    const bool second = wi >= gW;
    const float* W = second ? W2 : W1;
    u16* Wp = second ? w2p : w1p;
    const int tid = (second ? wi - gW : wi) * 256 + t;
    if (tid >= KOFF * 4096) return;
    const int k = tid >> 12;
    const int rem = tid & 4095;
    const int slot = rem >> 3;
    const int e = rem & 7;
    const int ks = slot >> 8;
    const int ct = (slot >> 6) & 3;
    const int lane = slot & 63;
    const int j = ks * 32 + ((lane >> 4) << 3) + e;
    const int c = ct * 16 + (lane & 15);
    Wp[tid] = f2bf(W[(k * 64 + j) * 64 + c]);
    return;
  }
  // feats cast
  const int idx = bid - gN - 2 * gW;
  if (idx == 0) {
    stats[t] = 0.f;
    if (t < 32) zbuf[t] = 0.f;
  }
  const int i = idx * 256 + t;
  if (i >= n4) return;
  const float4 v = reinterpret_cast<const float4*>(feats)[i];
  ushort4 o;
  o.x = f2bf(v.x); o.y = f2bf(v.y); o.z = f2bf(v.z); o.w = f2bf(v.w);
  reinterpret_cast<ushort4*>(featsb)[i] = o;
}

// ---------------- conv kernel ----------------
// R2's winning shape (4 waves x 64 voxels x 64 ch, barrier-free, direct B) with
// ONE change: the A-gather goes through a wave-private LDS double-buffer staged
// by global_load_lds in FULL-ROW form (8 lanes x 16B = one 128B row per instr,
// 64 L1 transactions/iter vs 128 for the direct-to-register frag gather), read
// back as MFMA fragments via XOR-swizzled conflict-free ds_read_b128.
// Load order per iter: B(k) oldest -> ids(k+2) -> stage A(k+1) newest, so every
// register wait is counted (vmcnt(24)/vmcnt(16)) and nothing ever drains.
__launch_bounds__(256, 2)
__global__ void k_conv(const u16* __restrict__ F, const u16* __restrict__ Wp,
                       const int* __restrict__ nbrT, const u16* __restrict__ zbuf,
                       float* __restrict__ out, float* __restrict__ stats, int N) {
  __shared__ u16 Ab[4][2][4096];  // 64 KB: [wave][buf][64 rows x 64 u16], row-swizzled
  __shared__ float sred[4][128];
  const int t = threadIdx.x;
  const int w = t >> 6;
  const int lane = t & 63;
  const int v0w = blockIdx.x * 256 + (w << 6);  // wave's first voxel
  const int lr = lane >> 3;                     // row within 8-row stage group
  const int swzch = ((lane & 7) ^ lr) << 3;     // pre-swizzled source chunk (u16)
  const u16* zsrc = zbuf + swzch;

  // fragment-read offsets (u16 units); row&7 == lane&7 for all frag rows
  const int r_lo = (lane & 15) << 6;
  const int p0 = (((lane >> 4) ^ (lane & 7)) << 3);
  const int p1 = (((4 ^ (lane >> 4)) ^ (lane & 7)) << 3);

  f32x4 acc[4][4];
#pragma unroll
  for (int m = 0; m < 4; ++m)
#pragma unroll
    for (int c = 0; c < 4; ++c) acc[m][c] = (f32x4){0.f, 0.f, 0.f, 0.f};

  u16* const buf0 = &Ab[w][0][0];
  u16* const buf1 = &Ab[w][1][0];
  const u16* bp = Wp + ((size_t)lane << 3);

  int idc[8], idn[8];

  // ---- prologue: ids(0) -> stage A(0) -> ids(1) ----
  {
    const int* np = nbrT;
#pragma unroll
    for (int i = 0; i < 8; ++i) {
      const int v = v0w + (i << 3) + lr;
      const int id_ = np[min(v, N - 1)];
      idc[i] = (v < N) ? id_ : -1;
    }
#pragma unroll
    for (int i = 0; i < 8; ++i) {
      const int id_ = idc[i];
      const u16* s = (id_ >= 0) ? F + ((size_t)(unsigned)id_ << 6) + swzch : zsrc;
      gload_lds16(s, buf0 + (i << 9));
    }
    const int* np1 = nbrT + (size_t)N;
#pragma unroll
    for (int i = 0; i < 8; ++i) {
      const int v = v0w + (i << 3) + lr;
      const int id_ = np1[min(v, N - 1)];
      idc[i] = (v < N) ? id_ : -1;  // ids for k=1 (stage at iter 0)
    }
  }

  auto conv_step = [&](int k, const u16* bufcur, u16* bufnxt,
                       int(&ids_st)[8], int(&ids_ld)[8]) __attribute__((always_inline)) {
    // 1. B(k) fragments (oldest VMEM of the iter; L1-resident broadcast)
    bf16x8 bfr[2][4];
    {
      const u16* bk = bp + ((size_t)k << 12);
#pragma unroll
      for (int ks = 0; ks < 2; ++ks)
#pragma unroll
        for (int c = 0; c < 4; ++c)
          bfr[ks][c] = *reinterpret_cast<const bf16x8*>(bk + (ks << 11) + (c << 9));
    }
    // 2. ids(k+2) (broadcast scalar loads)
    {
      const int* np = nbrT + (size_t)(k + 2) * N;
#pragma unroll
      for (int i = 0; i < 8; ++i) {
        const int v = v0w + (i << 3) + lr;
        const int id_ = np[min(v, N - 1)];
        ids_ld[i] = (v < N) ? id_ : -1;
      }
    }
    // 3. stage A(k+1): full 128B rows, linear LDS dest, pre-swizzled source
#pragma unroll
    for (int i = 0; i < 8; ++i) {
      const int id_ = ids_st[i];
      const u16* s = (id_ >= 0) ? F + ((size_t)(unsigned)id_ << 6) + swzch : zsrc;
      gload_lds16(s, bufnxt + (i << 9));
    }
    // 4. counted fence: 24 VMEM issued this iter -> A(k)'s stage (older) retired
    asm volatile("s_waitcnt vmcnt(24)" ::: "memory");
    // 5. A(k) fragments from LDS (swizzled, conflict-free)
    bf16x8 a0[4], a1[4];
#pragma unroll
    for (int m = 0; m < 4; ++m) {
      a0[m] = *reinterpret_cast<const bf16x8*>(bufcur + (m << 10) + r_lo + p0);
      a1[m] = *reinterpret_cast<const bf16x8*>(bufcur + (m << 10) + r_lo + p1);
    }
    // 6. MFMA (compiler: lgkmcnt for ds_reads, counted vmcnt(16) for B)
#pragma unroll
    for (int m = 0; m < 4; ++m)
#pragma unroll
      for (int c = 0; c < 4; ++c)
        acc[m][c] = __builtin_amdgcn_mfma_f32_16x16x32_bf16(a0[m], bfr[0][c], acc[m][c], 0, 0, 0);
#pragma unroll
    for (int m = 0; m < 4; ++m)
#pragma unroll
      for (int c = 0; c < 4; ++c)
        acc[m][c] = __builtin_amdgcn_mfma_f32_16x16x32_bf16(a1[m], bfr[1][c], acc[m][c], 0, 0, 0);
  };

  // ---- main loop: k = 0..25 in parity pairs, then uniform k = 26 ----
  for (int k = 0; k < 26; k += 2) {
    conv_step(k, buf0, buf1, idc, idn);
    conv_step(k + 1, buf1, buf0, idn, idc);
  }
  conv_step(26, buf0, buf1, idc, idn);  // stages plane-27 zeros, loads plane-28 (unused)

  // ---- store f32 + fused BN-stat partial reduction ----
  const int row0 = v0w + ((lane >> 4) << 2);
#pragma unroll
  for (int m = 0; m < 4; ++m) {
#pragma unroll
    for (int c = 0; c < 4; ++c) {
      const int col = (c << 4) + (lane & 15);
#pragma unroll
      for (int e = 0; e < 4; ++e) {
        const int v = row0 + (m << 4) + e;
        if (v < N) out[((size_t)v << 6) + col] = acc[m][c][e];
      }
    }
  }

#pragma unroll
  for (int c = 0; c < 4; ++c) {
    float s = 0.f, q = 0.f;
#pragma unroll
    for (int m = 0; m < 4; ++m)
#pragma unroll
      for (int e = 0; e < 4; ++e) {
        const float x = acc[m][c][e];  // OOB rows (zero-page) contribute exact 0
        s += x;
        q += x * x;
      }
    s += __shfl_xor(s, 16, 64);
    s += __shfl_xor(s, 32, 64);
    q += __shfl_xor(q, 16, 64);
    q += __shfl_xor(q, 32, 64);
    if (lane < 16) {
      sred[w][(c << 4) + lane] = s;
      sred[w][64 + (c << 4) + lane] = q;
    }
  }
  __syncthreads();
  if (t < 128) {
    const float tot = sred[0][t] + sred[1][t] + sred[2][t] + sred[3][t];
    atomicAdd(&stats[t], tot);
  }
}

// ---------------- BN finalize / apply ----------------

__global__ void k_final(const float* __restrict__ stats, const float* __restrict__ gamma,
                        const float* __restrict__ beta, float* __restrict__ sb, int N) {
  const int c = threadIdx.x;  // 64
  const float inv = 1.0f / (float)N;
  const float mu = stats[c] * inv;
  const float var = stats[64 + c] * inv - mu * mu;
  const float sc = gamma[c] * rsqrtf(var + EPSBN);
  sb[c] = sc;
  sb[64 + c] = beta[c] - mu * sc;
}

// y = relu(x*sc+bi) -> bf16 x_net
__global__ void k_apply1(const float* __restrict__ x, const float* __restrict__ sb,
                         u16* __restrict__ xb, int n4) {
  int i = blockIdx.x * 256 + threadIdx.x;
  if (i >= n4) return;
  const int cg = i & 15;
  float4 v = reinterpret_cast<const float4*>(x)[i];
  const float4 sc = reinterpret_cast<const float4*>(sb)[cg];
  const float4 bi = reinterpret_cast<const float4*>(sb)[16 + cg];
  float y0 = fmaxf(0.f, v.x * sc.x + bi.x);
  float y1 = fmaxf(0.f, v.y * sc.y + bi.y);
  float y2 = fmaxf(0.f, v.z * sc.z + bi.z);
  float y3 = fmaxf(0.f, v.w * sc.w + bi.w);
  ushort4 o;
  o.x = f2bf(y0); o.y = f2bf(y1); o.z = f2bf(y2); o.w = f2bf(y3);
  reinterpret_cast<ushort4*>(xb)[i] = o;
}

// out = x_net + relu(x*sc+bi)   (in-place on conv2 raw output)
__global__ void k_apply2(float* __restrict__ io, const float* __restrict__ sb,
                         const u16* __restrict__ xb, int n4) {
  int i = blockIdx.x * 256 + threadIdx.x;
  if (i >= n4) return;
  const int cg = i & 15;
  float4 v = reinterpret_cast<const float4*>(io)[i];
  const float4 sc = reinterpret_cast<const float4*>(sb)[cg];
  const float4 bi = reinterpret_cast<const float4*>(sb)[16 + cg];
  const ushort4 xn = reinterpret_cast<const ushort4*>(xb)[i];
  float4 o;
  o.x = bf2f(xn.x) + fmaxf(0.f, v.x * sc.x + bi.x);
  o.y = bf2f(xn.y) + fmaxf(0.f, v.y * sc.y + bi.y);
  o.z = bf2f(xn.z) + fmaxf(0.f, v.z * sc.z + bi.z);
  o.w = bf2f(xn.w) + fmaxf(0.f, v.w * sc.w + bi.w);
  reinterpret_cast<float4*>(io)[i] = o;
}

// ---------------- host ----------------

extern "C" void kernel_launch(void* const* d_in, const int* in_sizes, int n_in,
                              void* d_out, int out_size, void* d_ws, size_t ws_size,
                              hipStream_t stream) {
  const float* feats = (const float*)d_in[0];
  const float* W1 = (const float*)d_in[1];
  const float* g1 = (const float*)d_in[2];
  const float* b1 = (const float*)d_in[3];
  const float* W2 = (const float*)d_in[4];
  const float* g2 = (const float*)d_in[5];
  const float* b2 = (const float*)d_in[6];
  const int* nbr = (const int*)d_in[7];
  const int N = in_sizes[0] / 64;

  char* ws = (char*)d_ws;
  size_t off = 0;
  auto alloc = [&](size_t bytes) {
    void* p = ws + off;
    off = (off + bytes + 255) & ~(size_t)255;
    return p;
  };
  u16* featsb = (u16*)alloc((size_t)N * 64 * 2);
  u16* xnetb = (u16*)alloc((size_t)N * 64 * 2);
  u16* w1p = (u16*)alloc((size_t)KOFF * 4096 * 2);
  u16* w2p = (u16*)alloc((size_t)KOFF * 4096 * 2);
  float* stats = (float*)alloc(256 * 4);  // [s1 q1 s2 q2] x 64
  float* sb1 = (float*)alloc(128 * 4);
  float* sb2 = (float*)alloc(128 * 4);
  float* zbuf = (float*)alloc(128);       // 128B zero page for missing neighbors
  int* nbrT = (int*)alloc((size_t)(KOFF + 2) * N * 4);  // +plane27(-1) +plane28(garbage)
  float* outf = (float*)d_out;

  const int n4 = N * 16;
  const int gN = (N + 63) / 64;
  const int gPrep = (n4 + 255) / 256;
  const int gW = (KOFF * 4096 + 255) / 256;
  const int gConv = (N + 255) / 256;

  k_prep<<<gN + 2 * gW + gPrep, 256, 0, stream>>>(feats, W1, W2, nbr, featsb, w1p, w2p,
                                                  nbrT, stats, zbuf, N, gN, gW, n4);

  k_conv<<<gConv, 256, 0, stream>>>(featsb, w1p, nbrT, (const u16*)zbuf, outf, stats, N);
  k_final<<<1, 64, 0, stream>>>(stats, g1, b1, sb1, N);
  k_apply1<<<gPrep, 256, 0, stream>>>(outf, sb1, xnetb, n4);

  k_conv<<<gConv, 256, 0, stream>>>(xnetb, w2p, nbrT, (const u16*)zbuf, outf, stats + 128, N);
  k_final<<<1, 64, 0, stream>>>(stats + 128, g2, b2, sb2, N);
  k_apply2<<<gPrep, 256, 0, stream>>>(outf, sb2, xnetb, n4);
}

// Round 12
// 256.100 us; speedup vs baseline: 1.1326x; 1.1326x over previous
//
#include <hip/hip_runtime.h>
#include <cstdint>
#include <cstddef>

typedef unsigned short u16;
typedef __bf16 bf16x8 __attribute__((ext_vector_type(8)));
typedef float f32x4 __attribute__((ext_vector_type(4)));

#define KOFF 27
#define EPSBN 1e-5f

__device__ inline u16 f2bf(float f) {
  unsigned int u = __float_as_uint(f);
  unsigned int r = (u + 0x7FFFu + ((u >> 16) & 1u)) >> 16;  // RNE
  return (u16)r;
}
__device__ inline float bf2f(u16 h) {
  return __uint_as_float(((unsigned int)h) << 16);
}

// ---------------- fused prep kernel ----------------
// blocks [0, gN): transpose nbr [N,27] -> nbrT [27,N] (coalesced both sides)
// blocks [gN, gN+gW): pack W1 into MFMA B-frag order (bf16)
// blocks [gN+gW, gN+2gW): pack W2
// blocks [gN+2gW, ...): cast feats->bf16 (first block also zeroes stats[256])
__global__ void k_prep(const float* __restrict__ feats, const float* __restrict__ W1,
                       const float* __restrict__ W2, const int* __restrict__ nbr,
                       u16* __restrict__ featsb, u16* __restrict__ w1p,
                       u16* __restrict__ w2p, int* __restrict__ nbrT,
                       float* __restrict__ stats, int N, int gN, int gW, int n4) {
  __shared__ int L[64 * KOFF];
  const int t = threadIdx.x;
  const int bid = blockIdx.x;

  if (bid < gN) {  // neighbor transpose
    const int v0 = bid * 64;
    const int nv = min(64, N - v0);
    const int cnt = nv * KOFF;
    for (int i = t; i < cnt; i += 256) L[i] = nbr[(size_t)v0 * KOFF + i];
    __syncthreads();
    for (int i = t; i < KOFF * 64; i += 256) {
      int k = i >> 6, j = i & 63;
      if (j < nv) nbrT[(size_t)k * N + v0 + j] = L[j * KOFF + k];
    }
    return;
  }
  if (bid < gN + 2 * gW) {  // weight pack
    const int wi = bid - gN;
    const bool second = wi >= gW;
    const float* W = second ? W2 : W1;
    u16* Wp = second ? w2p : w1p;
    const int tid = (second ? wi - gW : wi) * 256 + t;
    if (tid >= KOFF * 4096) return;
    const int k = tid >> 12;
    const int rem = tid & 4095;
    const int slot = rem >> 3;
    const int e = rem & 7;
    const int ks = slot >> 8;
    const int ct = (slot >> 6) & 3;
    const int lane = slot & 63;
    const int j = ks * 32 + ((lane >> 4) << 3) + e;
    const int c = ct * 16 + (lane & 15);
    Wp[tid] = f2bf(W[(k * 64 + j) * 64 + c]);
    return;
  }
  // feats cast
  const int idx = bid - gN - 2 * gW;
  if (idx == 0) stats[t] = 0.f;
  const int i = idx * 256 + t;
  if (i >= n4) return;
  const float4 v = reinterpret_cast<const float4*>(feats)[i];
  ushort4 o;
  o.x = f2bf(v.x); o.y = f2bf(v.y); o.z = f2bf(v.z); o.w = f2bf(v.w);
  reinterpret_cast<ushort4*>(featsb)[i] = o;
}

// ---------------- conv kernel (verbatim R2/R10 — best measured: 93.5us) ----------------
// Block 256 = 4 waves; each wave owns 64 voxels x all 64 output channels.
// A-fragments gathered straight from global (16B/lane, frag-layout-native);
// B-fragments read straight from global (pre-packed, L1/L2-resident).
// Neighbor indices for k+1 prefetched (4 broadcast scalar loads). No barriers,
// no swizzle, no int4, no LDS staging (R3-R9,R11: all structural alternatives
// measured slower — this compiler-scheduled latency-bound loop is the floor
// at ~2.5 waves/SIMD, capped by the 64x64 tile's ~148 regs/wave).
// Epilogue fuses the BN batch-stat partial reduction (atomicAdd into stats[128]).
__launch_bounds__(256, 3)
__global__ void k_conv(const u16* __restrict__ F, const u16* __restrict__ Wp,
                       const int* __restrict__ nbrT, float* __restrict__ out,
                       float* __restrict__ stats, int N) {
  const int t = threadIdx.x;
  const int w = t >> 6;
  const int lane = t & 63;
  const int vbase = blockIdx.x * 256 + (w << 6) + (lane & 15);
  const int ch = (lane >> 4) << 3;  // A-frag channel offset (elements)

  f32x4 acc[4][4];
#pragma unroll
  for (int m = 0; m < 4; ++m)
#pragma unroll
    for (int c = 0; c < 4; ++c) acc[m][c] = (f32x4){0.f, 0.f, 0.f, 0.f};

  // prefetch k=0 neighbor indices
  int nid[4];
#pragma unroll
  for (int m = 0; m < 4; ++m) {
    const int v = vbase + (m << 4);
    nid[m] = (v < N) ? nbrT[v] : -1;
  }

  const u16* bp = Wp + ((size_t)lane << 3);

#pragma unroll 3
  for (int k = 0; k < KOFF; ++k) {
    // B fragments for this k (broadcast across waves -> L1/L2 hits)
    bf16x8 bfr[2][4];
#pragma unroll
    for (int ks = 0; ks < 2; ++ks)
#pragma unroll
      for (int c = 0; c < 4; ++c)
        bfr[ks][c] = *reinterpret_cast<const bf16x8*>(bp + ((size_t)k << 12) + (ks << 11) + (c << 9));

    // A fragments: direct register gather
    bf16x8 a0[4], a1[4];
#pragma unroll
    for (int m = 0; m < 4; ++m) {
      a0[m] = (bf16x8){};
      a1[m] = (bf16x8){};
      const int id = nid[m];
      if (id >= 0) {
        const u16* fr = F + ((size_t)id << 6) + ch;
        a0[m] = *reinterpret_cast<const bf16x8*>(fr);
        a1[m] = *reinterpret_cast<const bf16x8*>(fr + 32);
      }
    }

    // prefetch next k's indices (latency hidden under the MFMA block)
    if (k + 1 < KOFF) {
      const int* nk = nbrT + (size_t)(k + 1) * N;
#pragma unroll
      for (int m = 0; m < 4; ++m) {
        const int v = vbase + (m << 4);
        nid[m] = (v < N) ? nk[v] : -1;
      }
    }

#pragma unroll
    for (int m = 0; m < 4; ++m)
#pragma unroll
      for (int c = 0; c < 4; ++c)
        acc[m][c] = __builtin_amdgcn_mfma_f32_16x16x32_bf16(a0[m], bfr[0][c], acc[m][c], 0, 0, 0);
#pragma unroll
    for (int m = 0; m < 4; ++m)
#pragma unroll
      for (int c = 0; c < 4; ++c)
        acc[m][c] = __builtin_amdgcn_mfma_f32_16x16x32_bf16(a1[m], bfr[1][c], acc[m][c], 0, 0, 0);
  }

  // ---- store + fused BN-stat partial reduction ----
  const int row0 = blockIdx.x * 256 + (w << 6) + ((lane >> 4) << 2);
#pragma unroll
  for (int m = 0; m < 4; ++m) {
#pragma unroll
    for (int c = 0; c < 4; ++c) {
      const int col = (c << 4) + (lane & 15);
#pragma unroll
      for (int e = 0; e < 4; ++e) {
        const int v = row0 + (m << 4) + e;
        if (v < N) out[((size_t)v << 6) + col] = acc[m][c][e];
      }
    }
  }

  __shared__ float sred[4][128];
#pragma unroll
  for (int c = 0; c < 4; ++c) {
    float s = 0.f, q = 0.f;
#pragma unroll
    for (int m = 0; m < 4; ++m)
#pragma unroll
      for (int e = 0; e < 4; ++e) {
        const float x = acc[m][c][e];  // OOB rows contribute exact 0
        s += x;
        q += x * x;
      }
    s += __shfl_xor(s, 16, 64);
    s += __shfl_xor(s, 32, 64);
    q += __shfl_xor(q, 16, 64);
    q += __shfl_xor(q, 32, 64);
    if (lane < 16) {
      sred[w][(c << 4) + lane] = s;
      sred[w][64 + (c << 4) + lane] = q;
    }
  }
  __syncthreads();
  if (t < 128) {
    const float tot = sred[0][t] + sred[1][t] + sred[2][t] + sred[3][t];
    atomicAdd(&stats[t], tot);
  }
}

// ---------------- BN apply (k_final fused: scale/bias recomputed per thread) ----------------

// y = relu(x*sc+bi) -> bf16 x_net.  sc/bi derived inline from stats (broadcast
// L2-hot loads + 4 rsqrt/thread — noise for a memory-bound kernel; deletes the
// separate 1-block k_final launch and its serialization bubble).
__global__ void k_apply1(const float* __restrict__ x, const float* __restrict__ stats,
                         const float* __restrict__ gamma, const float* __restrict__ beta,
                         u16* __restrict__ xb, int n4, float invN) {
  int i = blockIdx.x * 256 + threadIdx.x;
  if (i >= n4) return;
  const int c0 = (i & 15) << 2;  // first of this thread's 4 channels
  float sc[4], bi[4];
#pragma unroll
  for (int j = 0; j < 4; ++j) {
    const int c = c0 + j;
    const float mu = stats[c] * invN;
    const float var = stats[64 + c] * invN - mu * mu;
    sc[j] = gamma[c] * rsqrtf(var + EPSBN);
    bi[j] = beta[c] - mu * sc[j];
  }
  const float4 v = reinterpret_cast<const float4*>(x)[i];
  float y0 = fmaxf(0.f, v.x * sc[0] + bi[0]);
  float y1 = fmaxf(0.f, v.y * sc[1] + bi[1]);
  float y2 = fmaxf(0.f, v.z * sc[2] + bi[2]);
  float y3 = fmaxf(0.f, v.w * sc[3] + bi[3]);
  ushort4 o;
  o.x = f2bf(y0); o.y = f2bf(y1); o.z = f2bf(y2); o.w = f2bf(y3);
  reinterpret_cast<ushort4*>(xb)[i] = o;
}

// out = x_net + relu(x*sc+bi)   (in-place on conv2 raw output)
__global__ void k_apply2(float* __restrict__ io, const float* __restrict__ stats,
                         const float* __restrict__ gamma, const float* __restrict__ beta,
                         const u16* __restrict__ xb, int n4, float invN) {
  int i = blockIdx.x * 256 + threadIdx.x;
  if (i >= n4) return;
  const int c0 = (i & 15) << 2;
  float sc[4], bi[4];
#pragma unroll
  for (int j = 0; j < 4; ++j) {
    const int c = c0 + j;
    const float mu = stats[c] * invN;
    const float var = stats[64 + c] * invN - mu * mu;
    sc[j] = gamma[c] * rsqrtf(var + EPSBN);
    bi[j] = beta[c] - mu * sc[j];
  }
  const float4 v = reinterpret_cast<const float4*>(io)[i];
  const ushort4 xn = reinterpret_cast<const ushort4*>(xb)[i];
  float4 o;
  o.x = bf2f(xn.x) + fmaxf(0.f, v.x * sc[0] + bi[0]);
  o.y = bf2f(xn.y) + fmaxf(0.f, v.y * sc[1] + bi[1]);
  o.z = bf2f(xn.z) + fmaxf(0.f, v.z * sc[2] + bi[2]);
  o.w = bf2f(xn.w) + fmaxf(0.f, v.w * sc[3] + bi[3]);
  reinterpret_cast<float4*>(io)[i] = o;
}

// ---------------- host ----------------

extern "C" void kernel_launch(void* const* d_in, const int* in_sizes, int n_in,
                              void* d_out, int out_size, void* d_ws, size_t ws_size,
                              hipStream_t stream) {
  const float* feats = (const float*)d_in[0];
  const float* W1 = (const float*)d_in[1];
  const float* g1 = (const float*)d_in[2];
  const float* b1 = (const float*)d_in[3];
  const float* W2 = (const float*)d_in[4];
  const float* g2 = (const float*)d_in[5];
  const float* b2 = (const float*)d_in[6];
  const int* nbr = (const int*)d_in[7];
  const int N = in_sizes[0] / 64;

  char* ws = (char*)d_ws;
  size_t off = 0;
  auto alloc = [&](size_t bytes) {
    void* p = ws + off;
    off = (off + bytes + 255) & ~(size_t)255;
    return p;
  };
  u16* featsb = (u16*)alloc((size_t)N * 64 * 2);
  u16* xnetb = (u16*)alloc((size_t)N * 64 * 2);
  u16* w1p = (u16*)alloc((size_t)KOFF * 4096 * 2);
  u16* w2p = (u16*)alloc((size_t)KOFF * 4096 * 2);
  float* stats = (float*)alloc(256 * 4);  // [s1 q1 s2 q2] x 64
  int* nbrT = (int*)alloc((size_t)KOFF * N * 4);
  float* outf = (float*)d_out;

  const int n4 = N * 16;
  const float invN = 1.0f / (float)N;
  const int gN = (N + 63) / 64;
  const int gPrep = (n4 + 255) / 256;
  const int gW = (KOFF * 4096 + 255) / 256;
  const int gConv = (N + 255) / 256;

  k_prep<<<gN + 2 * gW + gPrep, 256, 0, stream>>>(feats, W1, W2, nbr, featsb, w1p, w2p,
                                                  nbrT, stats, N, gN, gW, n4);

  k_conv<<<gConv, 256, 0, stream>>>(featsb, w1p, nbrT, outf, stats, N);
  k_apply1<<<gPrep, 256, 0, stream>>>(outf, stats, g1, b1, xnetb, n4, invN);

  k_conv<<<gConv, 256, 0, stream>>>(xnetb, w2p, nbrT, outf, stats + 128, N);
  k_apply2<<<gPrep, 256, 0, stream>>>(outf, stats + 128, g2, b2, xnetb, n4, invN);
}

// Round 13
// 248.812 us; speedup vs baseline: 1.1657x; 1.0293x over previous
//
#include <hip/hip_runtime.h>
#include <cstdint>
#include <cstddef>

typedef unsigned short u16;
typedef __bf16 bf16x8 __attribute__((ext_vector_type(8)));
typedef float f32x4 __attribute__((ext_vector_type(4)));

#define KOFF 27
#define EPSBN 1e-5f

__device__ inline u16 f2bf(float f) {
  unsigned int u = __float_as_uint(f);
  unsigned int r = (u + 0x7FFFu + ((u >> 16) & 1u)) >> 16;  // RNE
  return (u16)r;
}
__device__ inline float bf2f(u16 h) {
  return __uint_as_float(((unsigned int)h) << 16);
}

// ---------------- fused prep kernel ----------------
// blocks [0, gN): transpose nbr [N,27] -> nbrT [27,N] (coalesced both sides)
// blocks [gN, gN+gW): pack W1 into MFMA B-frag order (bf16)
// blocks [gN+gW, gN+2gW): pack W2
// blocks [gN+2gW, ...): cast feats->bf16 (first block also zeroes stats[256])
__global__ void k_prep(const float* __restrict__ feats, const float* __restrict__ W1,
                       const float* __restrict__ W2, const int* __restrict__ nbr,
                       u16* __restrict__ featsb, u16* __restrict__ w1p,
                       u16* __restrict__ w2p, int* __restrict__ nbrT,
                       float* __restrict__ stats, int N, int gN, int gW, int n4) {
  __shared__ int L[64 * KOFF];
  const int t = threadIdx.x;
  const int bid = blockIdx.x;

  if (bid < gN) {  // neighbor transpose
    const int v0 = bid * 64;
    const int nv = min(64, N - v0);
    const int cnt = nv * KOFF;
    for (int i = t; i < cnt; i += 256) L[i] = nbr[(size_t)v0 * KOFF + i];
    __syncthreads();
    for (int i = t; i < KOFF * 64; i += 256) {
      int k = i >> 6, j = i & 63;
      if (j < nv) nbrT[(size_t)k * N + v0 + j] = L[j * KOFF + k];
    }
    return;
  }
  if (bid < gN + 2 * gW) {  // weight pack
    const int wi = bid - gN;
    const bool second = wi >= gW;
    const float* W = second ? W2 : W1;
    u16* Wp = second ? w2p : w1p;
    const int tid = (second ? wi - gW : wi) * 256 + t;
    if (tid >= KOFF * 4096) return;
    const int k = tid >> 12;
    const int rem = tid & 4095;
    const int slot = rem >> 3;
    const int e = rem & 7;
    const int ks = slot >> 8;
    const int ct = (slot >> 6) & 3;
    const int lane = slot & 63;
    const int j = ks * 32 + ((lane >> 4) << 3) + e;
    const int c = ct * 16 + (lane & 15);
    Wp[tid] = f2bf(W[(k * 64 + j) * 64 + c]);
    return;
  }
  // feats cast
  const int idx = bid - gN - 2 * gW;
  if (idx == 0) stats[t] = 0.f;
  const int i = idx * 256 + t;
  if (i >= n4) return;
  const float4 v = reinterpret_cast<const float4*>(feats)[i];
  ushort4 o;
  o.x = f2bf(v.x); o.y = f2bf(v.y); o.z = f2bf(v.z); o.w = f2bf(v.w);
  reinterpret_cast<ushort4*>(featsb)[i] = o;
}

// ---------------- conv kernel (R2/R10 loop, bf16 paired-store epilogue) ----------------
// Block 256 = 4 waves; each wave owns 64 voxels x all 64 output channels.
// Main loop byte-identical to R12's (best measured: ~96us, MfmaUtil 28%).
// Epilogue change only: raw output stored as bf16 via lane-pair packing —
// __shfl_xor(1) brings the adjacent column (C/D layout: adjacent cols live in
// adjacent lanes), even lanes store aligned u32 (2 cols). Active lanes per store
// cover contiguous 32B segments; c-innermost ordering completes each 128B line
// in adjacent instructions -> write-combining preserved (R3's 2B-scalar-store
// RMW inflation avoided). Halves conv WRITE (75.6 -> ~38MB) + apply reads.
// Stats still reduced from the exact f32 accumulators.
__launch_bounds__(256, 3)
__global__ void k_conv(const u16* __restrict__ F, const u16* __restrict__ Wp,
                       const int* __restrict__ nbrT, u16* __restrict__ rawout,
                       float* __restrict__ stats, int N) {
  const int t = threadIdx.x;
  const int w = t >> 6;
  const int lane = t & 63;
  const int vbase = blockIdx.x * 256 + (w << 6) + (lane & 15);
  const int ch = (lane >> 4) << 3;  // A-frag channel offset (elements)

  f32x4 acc[4][4];
#pragma unroll
  for (int m = 0; m < 4; ++m)
#pragma unroll
    for (int c = 0; c < 4; ++c) acc[m][c] = (f32x4){0.f, 0.f, 0.f, 0.f};

  // prefetch k=0 neighbor indices
  int nid[4];
#pragma unroll
  for (int m = 0; m < 4; ++m) {
    const int v = vbase + (m << 4);
    nid[m] = (v < N) ? nbrT[v] : -1;
  }

  const u16* bp = Wp + ((size_t)lane << 3);

#pragma unroll 3
  for (int k = 0; k < KOFF; ++k) {
    // B fragments for this k (broadcast across waves -> L1/L2 hits)
    bf16x8 bfr[2][4];
#pragma unroll
    for (int ks = 0; ks < 2; ++ks)
#pragma unroll
      for (int c = 0; c < 4; ++c)
        bfr[ks][c] = *reinterpret_cast<const bf16x8*>(bp + ((size_t)k << 12) + (ks << 11) + (c << 9));

    // A fragments: direct register gather
    bf16x8 a0[4], a1[4];
#pragma unroll
    for (int m = 0; m < 4; ++m) {
      a0[m] = (bf16x8){};
      a1[m] = (bf16x8){};
      const int id = nid[m];
      if (id >= 0) {
        const u16* fr = F + ((size_t)id << 6) + ch;
        a0[m] = *reinterpret_cast<const bf16x8*>(fr);
        a1[m] = *reinterpret_cast<const bf16x8*>(fr + 32);
      }
    }

    // prefetch next k's indices (latency hidden under the MFMA block)
    if (k + 1 < KOFF) {
      const int* nk = nbrT + (size_t)(k + 1) * N;
#pragma unroll
      for (int m = 0; m < 4; ++m) {
        const int v = vbase + (m << 4);
        nid[m] = (v < N) ? nk[v] : -1;
      }
    }

#pragma unroll
    for (int m = 0; m < 4; ++m)
#pragma unroll
      for (int c = 0; c < 4; ++c)
        acc[m][c] = __builtin_amdgcn_mfma_f32_16x16x32_bf16(a0[m], bfr[0][c], acc[m][c], 0, 0, 0);
#pragma unroll
    for (int m = 0; m < 4; ++m)
#pragma unroll
      for (int c = 0; c < 4; ++c)
        acc[m][c] = __builtin_amdgcn_mfma_f32_16x16x32_bf16(a1[m], bfr[1][c], acc[m][c], 0, 0, 0);
  }

  // ---- bf16 paired store + fused BN-stat partial reduction ----
  const int row0 = blockIdx.x * 256 + (w << 6) + ((lane >> 4) << 2);
  const bool evenlane = (lane & 1) == 0;
#pragma unroll
  for (int m = 0; m < 4; ++m) {
#pragma unroll
    for (int e = 0; e < 4; ++e) {
      const int v = row0 + (m << 4) + e;
#pragma unroll
      for (int c = 0; c < 4; ++c) {
        const unsigned myb = (unsigned)f2bf(acc[m][c][e]);
        const unsigned ob = (unsigned)__shfl_xor((int)myb, 1, 64);
        if (evenlane && v < N) {
          const int col = (c << 4) + (lane & 15);  // even col; u32 covers (col, col+1)
          *reinterpret_cast<unsigned*>(rawout + ((size_t)v << 6) + col) = myb | (ob << 16);
        }
      }
    }
  }

  __shared__ float sred[4][128];
#pragma unroll
  for (int c = 0; c < 4; ++c) {
    float s = 0.f, q = 0.f;
#pragma unroll
    for (int m = 0; m < 4; ++m)
#pragma unroll
      for (int e = 0; e < 4; ++e) {
        const float x = acc[m][c][e];  // OOB rows contribute exact 0
        s += x;
        q += x * x;
      }
    s += __shfl_xor(s, 16, 64);
    s += __shfl_xor(s, 32, 64);
    q += __shfl_xor(q, 16, 64);
    q += __shfl_xor(q, 32, 64);
    if (lane < 16) {
      sred[w][(c << 4) + lane] = s;
      sred[w][64 + (c << 4) + lane] = q;
    }
  }
  __syncthreads();
  if (t < 128) {
    const float tot = sred[0][t] + sred[1][t] + sred[2][t] + sred[3][t];
    atomicAdd(&stats[t], tot);
  }
}

// ---------------- BN apply (k_final fused; raw input is bf16, 8 elems/thread) ----------------

// x_net = relu(raw*sc+bi) -> bf16
__global__ void k_apply1(const u16* __restrict__ raw, const float* __restrict__ stats,
                         const float* __restrict__ gamma, const float* __restrict__ beta,
                         u16* __restrict__ xb, int n8, float invN) {
  int i = blockIdx.x * 256 + threadIdx.x;
  if (i >= n8) return;
  const int c0 = (i & 7) << 3;  // first of this thread's 8 channels
  float sc[8], bi[8];
#pragma unroll
  for (int j = 0; j < 8; ++j) {
    const int c = c0 + j;
    const float mu = stats[c] * invN;
    const float var = stats[64 + c] * invN - mu * mu;
    sc[j] = gamma[c] * rsqrtf(var + EPSBN);
    bi[j] = beta[c] - mu * sc[j];
  }
  const uint4 rv = reinterpret_cast<const uint4*>(raw)[i];
  const unsigned vals[4] = {rv.x, rv.y, rv.z, rv.w};
  unsigned ov[4];
#pragma unroll
  for (int j = 0; j < 4; ++j) {
    const float lo = bf2f((u16)(vals[j] & 0xffff));
    const float hi = bf2f((u16)(vals[j] >> 16));
    const float y0 = fmaxf(0.f, lo * sc[2 * j] + bi[2 * j]);
    const float y1 = fmaxf(0.f, hi * sc[2 * j + 1] + bi[2 * j + 1]);
    ov[j] = (unsigned)f2bf(y0) | ((unsigned)f2bf(y1) << 16);
  }
  reinterpret_cast<uint4*>(xb)[i] = make_uint4(ov[0], ov[1], ov[2], ov[3]);
}

// out = x_net + relu(raw*sc+bi)   (raw, x_net bf16 -> out f32)
__global__ void k_apply2(const u16* __restrict__ raw, const float* __restrict__ stats,
                         const float* __restrict__ gamma, const float* __restrict__ beta,
                         const u16* __restrict__ xb, float* __restrict__ out, int n8,
                         float invN) {
  int i = blockIdx.x * 256 + threadIdx.x;
  if (i >= n8) return;
  const int c0 = (i & 7) << 3;
  float sc[8], bi[8];
#pragma unroll
  for (int j = 0; j < 8; ++j) {
    const int c = c0 + j;
    const float mu = stats[c] * invN;
    const float var = stats[64 + c] * invN - mu * mu;
    sc[j] = gamma[c] * rsqrtf(var + EPSBN);
    bi[j] = beta[c] - mu * sc[j];
  }
  const uint4 rv = reinterpret_cast<const uint4*>(raw)[i];
  const uint4 xv = reinterpret_cast<const uint4*>(xb)[i];
  const unsigned rvals[4] = {rv.x, rv.y, rv.z, rv.w};
  const unsigned xvals[4] = {xv.x, xv.y, xv.z, xv.w};
  float o[8];
#pragma unroll
  for (int j = 0; j < 4; ++j) {
    const float rlo = bf2f((u16)(rvals[j] & 0xffff));
    const float rhi = bf2f((u16)(rvals[j] >> 16));
    o[2 * j] = bf2f((u16)(xvals[j] & 0xffff)) + fmaxf(0.f, rlo * sc[2 * j] + bi[2 * j]);
    o[2 * j + 1] = bf2f((u16)(xvals[j] >> 16)) + fmaxf(0.f, rhi * sc[2 * j + 1] + bi[2 * j + 1]);
  }
  reinterpret_cast<float4*>(out)[2 * i] = make_float4(o[0], o[1], o[2], o[3]);
  reinterpret_cast<float4*>(out)[2 * i + 1] = make_float4(o[4], o[5], o[6], o[7]);
}

// ---------------- host ----------------

extern "C" void kernel_launch(void* const* d_in, const int* in_sizes, int n_in,
                              void* d_out, int out_size, void* d_ws, size_t ws_size,
                              hipStream_t stream) {
  const float* feats = (const float*)d_in[0];
  const float* W1 = (const float*)d_in[1];
  const float* g1 = (const float*)d_in[2];
  const float* b1 = (const float*)d_in[3];
  const float* W2 = (const float*)d_in[4];
  const float* g2 = (const float*)d_in[5];
  const float* b2 = (const float*)d_in[6];
  const int* nbr = (const int*)d_in[7];
  const int N = in_sizes[0] / 64;

  char* ws = (char*)d_ws;
  size_t off = 0;
  auto alloc = [&](size_t bytes) {
    void* p = ws + off;
    off = (off + bytes + 255) & ~(size_t)255;
    return p;
  };
  u16* featsb = (u16*)alloc((size_t)N * 64 * 2);
  u16* xnetb = (u16*)alloc((size_t)N * 64 * 2);
  u16* w1p = (u16*)alloc((size_t)KOFF * 4096 * 2);
  u16* w2p = (u16*)alloc((size_t)KOFF * 4096 * 2);
  float* stats = (float*)alloc(256 * 4);  // [s1 q1 s2 q2] x 64
  int* nbrT = (int*)alloc((size_t)KOFF * N * 4);

  u16* raw1 = (u16*)d_out;  // conv1 raw bf16 scribbled into d_out (overwritten later)
  u16* raw2 = featsb;       // conv2 raw bf16 reuses dead conv1-input buffer
  float* outf = (float*)d_out;

  const int n4 = N * 16;
  const int n8 = N * 8;
  const float invN = 1.0f / (float)N;
  const int gN = (N + 63) / 64;
  const int gPrep = (n4 + 255) / 256;
  const int gApply = (n8 + 255) / 256;
  const int gW = (KOFF * 4096 + 255) / 256;
  const int gConv = (N + 255) / 256;

  k_prep<<<gN + 2 * gW + gPrep, 256, 0, stream>>>(feats, W1, W2, nbr, featsb, w1p, w2p,
                                                  nbrT, stats, N, gN, gW, n4);

  k_conv<<<gConv, 256, 0, stream>>>(featsb, w1p, nbrT, raw1, stats, N);
  k_apply1<<<gApply, 256, 0, stream>>>(raw1, stats, g1, b1, xnetb, n8, invN);

  k_conv<<<gConv, 256, 0, stream>>>(xnetb, w2p, nbrT, raw2, stats + 128, N);
  k_apply2<<<gApply, 256, 0, stream>>>(raw2, stats + 128, g2, b2, xnetb, outf, n8, invN);
}